// Round 1
// baseline (273.589 us; speedup 1.0000x reference)
//
#include <hip/hip_runtime.h>
#include <math.h>

// Padded LDS index: breaks power-of-2 strides; injective for e in [0,256) -> [0,271)
#define PIDX(e) ((e) + ((e) >> 4))

__device__ __forceinline__ float2 cadd(float2 a, float2 b) { return {a.x + b.x, a.y + b.y}; }
__device__ __forceinline__ float2 csub(float2 a, float2 b) { return {a.x - b.x, a.y - b.y}; }
__device__ __forceinline__ float2 cmul(float2 a, float2 b) {
    return {a.x * b.x - a.y * b.y, a.x * b.y + a.y * b.x};
}

// 256-point Stockham radix-4 FFT, 64 threads per row, data in padded LDS buffers.
// Result ends up back in Xr (natural order). All threads of the block must call
// (barriers are uniform); inactive lanes pass active=false.
__device__ __forceinline__ void fft256_stages(float2* Xr, float2* Yr, int t, bool active) {
    float2* sbuf = Xr;
    float2* dbuf = Yr;
#pragma unroll
    for (int s = 0; s < 4; ++s) {
        if (active) {
            const int sh = 2 * s;
            const int mm = 1 << sh;       // 1,4,16,64
            const int ll = 64 >> sh;      // 64,16,4,1
            const int jj = t >> sh;       // j in [0,l)
            const int kk = t & (mm - 1);  // k in [0,m)
            float2 c0 = sbuf[PIDX(kk + mm * jj)];
            float2 c1 = sbuf[PIDX(kk + mm * (jj + ll))];
            float2 c2 = sbuf[PIDX(kk + mm * (jj + 2 * ll))];
            float2 c3 = sbuf[PIDX(kk + mm * (jj + 3 * ll))];
            float2 sa = cadd(c0, c2);
            float2 sb = csub(c0, c2);
            float2 sc = cadd(c1, c3);
            float2 sd = {c1.y - c3.y, c3.x - c1.x};  // -i*(c1-c3)
            float2 d0 = cadd(sa, sc);
            float2 d1 = cadd(sb, sd);
            float2 d2 = csub(sa, sc);
            float2 d3 = csub(sb, sd);
            // w = exp(-2*pi*i * jj / (4*ll)) = exp(-i * (2pi/256) * (jj << sh))
            const float ang = -0.024543692606170259f * (float)(jj << sh);
            float sy, cx;
            __sincosf(ang, &sy, &cx);
            float2 w1 = {cx, sy};
            float2 w2 = cmul(w1, w1);
            float2 w3 = cmul(w2, w1);
            const int ob = kk + 4 * mm * jj;
            dbuf[PIDX(ob)] = d0;
            dbuf[PIDX(ob + mm)] = cmul(w1, d1);
            dbuf[PIDX(ob + 2 * mm)] = cmul(w2, d2);
            dbuf[PIDX(ob + 3 * mm)] = cmul(w3, d3);
        }
        __syncthreads();
        float2* tmp = sbuf;
        sbuf = dbuf;
        dbuf = tmp;
    }
}

// Kernel 1: per image job (pair x channel), compute row FFTs of the real
// difference image; keep v=0..128; write transposed [img][v][r] to ws.
// grid = (16 row-chunks, nimg), block = 256 (4 rows x 64 threads per iter, 4 iters)
__global__ __launch_bounds__(256) void k_rowfft(const float* __restrict__ A,
                                                const float* __restrict__ P,
                                                const float* __restrict__ N,
                                                const int* __restrict__ negIdx,
                                                float2* __restrict__ ws, int img0) {
    __shared__ float2 Xb[4][272];
    __shared__ float2 Yb[4][272];
    __shared__ float2 outT[129 * 17];  // [v][slot], stride 17 to dodge bank conflicts

    const int img = img0 + blockIdx.y;
    const int pair = img / 3;
    const int ch = img - pair * 3;
    int i, jn;
    const float* S;
    if (pair < 32) {  // anchor-positive pairs: j == i
        i = pair;
        jn = pair;
        S = P;
    } else {  // anchor-negative pairs: j = neg_idx[i][k]
        const int t2 = pair - 32;
        i = t2 >> 1;
        jn = negIdx[(i << 1) + (t2 & 1)];
        S = N;
    }
    const float* abase = A + ((size_t)(i * 3 + ch) << 16);
    const float* sbase = S + ((size_t)(jn * 3 + ch) << 16);

    const int tid = threadIdx.x;
    const int rr = tid >> 6;   // row slot within group of 4
    const int t = tid & 63;    // lane within row
    const int r0 = blockIdx.x * 16;

    for (int it = 0; it < 4; ++it) {
        const int r = r0 + it * 4 + rr;
        const float4 av = *(const float4*)(abase + (r << 8) + (t << 2));
        const float4 sv = *(const float4*)(sbase + (r << 8) + (t << 2));
        const int e0 = t << 2;
        Xb[rr][PIDX(e0 + 0)] = {av.x - sv.x, 0.f};
        Xb[rr][PIDX(e0 + 1)] = {av.y - sv.y, 0.f};
        Xb[rr][PIDX(e0 + 2)] = {av.z - sv.z, 0.f};
        Xb[rr][PIDX(e0 + 3)] = {av.w - sv.w, 0.f};
        __syncthreads();
        fft256_stages(Xb[rr], Yb[rr], t, true);
        // stash v = t, t+64, (t==0: 128) into transposed staging
        const int slot = it * 4 + rr;
        outT[t * 17 + slot] = Xb[rr][PIDX(t)];
        outT[(t + 64) * 17 + slot] = Xb[rr][PIDX(t + 64)];
        if (t == 0) outT[128 * 17 + slot] = Xb[rr][PIDX(128)];
        __syncthreads();  // protect Xb reuse next iter + outT completeness
    }

    // write [v][r0..r0+15] chunks: 128B contiguous per v
    float2* g = ws + (size_t)blockIdx.y * (129 * 256);
    for (int e = tid; e < 129 * 16; e += 256) {
        const int v = e >> 4, rl = e & 15;
        g[v * 256 + r0 + rl] = outT[v * 17 + rl];
    }
}

// Kernel 2: column FFTs (complex 256-pt) + weighted magnitude sum -> acc[pair].
// grid = (33, nimg), block = 256 = 4 waves, one column per wave.
__global__ __launch_bounds__(256) void k_colfft(const float2* __restrict__ ws,
                                                float* __restrict__ acc, int img0) {
    __shared__ float2 Xb[4][272];
    __shared__ float2 Yb[4][272];
    const int tid = threadIdx.x;
    const int w = tid >> 6, t = tid & 63;
    const int v = blockIdx.x * 4 + w;
    const bool active = v < 129;
    const float2* g = ws + ((size_t)blockIdx.y * 129 + (active ? v : 0)) * 256;
    if (active) {
#pragma unroll
        for (int q = 0; q < 4; ++q) Xb[w][PIDX(t + 64 * q)] = g[t + 64 * q];
    }
    __syncthreads();
    fft256_stages(Xb[w], Yb[w], t, active);
    if (active) {
        float ssum = 0.f;
#pragma unroll
        for (int q = 0; q < 4; ++q) {
            const float2 z = Xb[w][PIDX(t + 64 * q)];
            ssum += sqrtf(z.x * z.x + z.y * z.y);
        }
#pragma unroll
        for (int off = 32; off; off >>= 1) ssum += __shfl_down(ssum, off);
        if (t == 0) {
            const int img = img0 + blockIdx.y;
            const int pair = img / 3;
            const float wgt = (v == 0 || v == 128) ? 1.f : 2.f;  // Hermitian symmetry weight
            atomicAdd(&acc[pair], ssum * wgt);
        }
    }
}

__global__ void k_zero(float* acc) {
    if (threadIdx.x < 96) acc[threadIdx.x] = 0.f;
}

// acc[0..31] = sum|FFT(a-p)| per i;  acc[32 + 2i + k] = sum|FFT(a_i - n_j)|
__global__ void k_final(const float* __restrict__ acc, float* __restrict__ out) {
    const int t = threadIdx.x;  // 64 threads: t = 2i+k
    const float inv = 1.f / 196608.f;  // mean over C*H*W
    const float dap = acc[t >> 1] * inv;
    const float dan = acc[32 + t] * inv + 1e-7f;
    float val = dap / dan;
#pragma unroll
    for (int off = 32; off; off >>= 1) val += __shfl_down(val, off);
    if (t == 0) out[0] = val * (1.f / 64.f);  // / (MULTI_N_NUM * B)
}

extern "C" void kernel_launch(void* const* d_in, const int* in_sizes, int n_in,
                              void* d_out, int out_size, void* d_ws, size_t ws_size,
                              hipStream_t stream) {
    const float* A = (const float*)d_in[0];
    const float* P = (const float*)d_in[1];
    const float* N = (const float*)d_in[2];
    const int* negIdx = (const int*)d_in[3];

    float* acc = (float*)d_ws;
    float2* inter = (float2*)((char*)d_ws + 512);
    const size_t perImg = (size_t)129 * 256 * sizeof(float2);  // 264192 B
    size_t avail = ws_size > 512 ? ws_size - 512 : 0;
    int cap = (int)(avail / perImg);
    if (cap > 288) cap = 288;
    if (cap < 1) cap = 1;  // last resort

    k_zero<<<1, 128, 0, stream>>>(acc);
    for (int img0 = 0; img0 < 288; img0 += cap) {
        const int nimg = (288 - img0 < cap) ? (288 - img0) : cap;
        dim3 g1(16, nimg);
        k_rowfft<<<g1, dim3(256), 0, stream>>>(A, P, N, negIdx, inter, img0);
        dim3 g2(33, nimg);
        k_colfft<<<g2, dim3(256), 0, stream>>>(inter, acc, img0);
    }
    k_final<<<1, 64, 0, stream>>>(acc, (float*)d_out);
}

// Round 5
// 76.770 us; speedup vs baseline: 3.5637x; 3.5637x over previous
//
#include <hip/hip_runtime.h>
#include <math.h>

// Padded LDS index: breaks power-of-2 strides; injective for e in [0,256) -> [0,271)
#define PIDX(e) ((e) + ((e) >> 4))

__device__ __forceinline__ float2 cadd(float2 a, float2 b) { return {a.x + b.x, a.y + b.y}; }
__device__ __forceinline__ float2 csub(float2 a, float2 b) { return {a.x - b.x, a.y - b.y}; }
__device__ __forceinline__ float2 cmul(float2 a, float2 b) {
    return {a.x * b.x - a.y * b.y, a.x * b.y + a.y * b.x};
}

// 256-point Stockham radix-4 FFT, 64 threads per row, data in padded LDS buffers.
// Result ends up back in Xr (natural order). All threads of the block must call
// (barriers are uniform); inactive lanes pass active=false.
__device__ __forceinline__ void fft256_stages(float2* Xr, float2* Yr, int t, bool active) {
    float2* sbuf = Xr;
    float2* dbuf = Yr;
#pragma unroll
    for (int s = 0; s < 4; ++s) {
        if (active) {
            const int sh = 2 * s;
            const int mm = 1 << sh;       // 1,4,16,64
            const int ll = 64 >> sh;      // 64,16,4,1
            const int jj = t >> sh;       // j in [0,l)
            const int kk = t & (mm - 1);  // k in [0,m)
            float2 c0 = sbuf[PIDX(kk + mm * jj)];
            float2 c1 = sbuf[PIDX(kk + mm * (jj + ll))];
            float2 c2 = sbuf[PIDX(kk + mm * (jj + 2 * ll))];
            float2 c3 = sbuf[PIDX(kk + mm * (jj + 3 * ll))];
            float2 sa = cadd(c0, c2);
            float2 sb = csub(c0, c2);
            float2 sc = cadd(c1, c3);
            float2 sd = {c1.y - c3.y, c3.x - c1.x};  // -i*(c1-c3)
            float2 d0 = cadd(sa, sc);
            float2 d1 = cadd(sb, sd);
            float2 d2 = csub(sa, sc);
            float2 d3 = csub(sb, sd);
            // w = exp(-2*pi*i * jj / (4*ll)) = exp(-i * (2pi/256) * (jj << sh))
            const float ang = -0.024543692606170259f * (float)(jj << sh);
            float sy, cx;
            __sincosf(ang, &sy, &cx);
            float2 w1 = {cx, sy};
            float2 w2 = cmul(w1, w1);
            float2 w3 = cmul(w2, w1);
            const int ob = kk + 4 * mm * jj;
            dbuf[PIDX(ob)] = d0;
            dbuf[PIDX(ob + mm)] = cmul(w1, d1);
            dbuf[PIDX(ob + 2 * mm)] = cmul(w2, d2);
            dbuf[PIDX(ob + 3 * mm)] = cmul(w3, d3);
        }
        __syncthreads();
        float2* tmp = sbuf;
        sbuf = dbuf;
        dbuf = tmp;
    }
}

// Kernel 1: per image job (pair x channel), compute row FFTs of the real
// difference image; keep v=0..128; write transposed [img][v][r] to ws.
// grid = (16 row-chunks, nimg), block = 256 (4 rows x 64 threads per iter, 4 iters)
__global__ __launch_bounds__(256) void k_rowfft(const float* __restrict__ A,
                                                const float* __restrict__ P,
                                                const float* __restrict__ N,
                                                const int* __restrict__ negIdx,
                                                float2* __restrict__ ws, int img0) {
    __shared__ float2 Xb[4][272];
    __shared__ float2 Yb[4][272];
    __shared__ float2 outT[129 * 17];  // [v][slot], stride 17 to dodge bank conflicts

    const int img = img0 + blockIdx.y;
    const int pair = img / 3;
    const int ch = img - pair * 3;
    int i, jn;
    const float* S;
    if (pair < 32) {  // anchor-positive pairs: j == i
        i = pair;
        jn = pair;
        S = P;
    } else {  // anchor-negative pairs: j = neg_idx[i][k]
        const int t2 = pair - 32;
        i = t2 >> 1;
        jn = negIdx[(i << 1) + (t2 & 1)];
        S = N;
    }
    const float* abase = A + ((size_t)(i * 3 + ch) << 16);
    const float* sbase = S + ((size_t)(jn * 3 + ch) << 16);

    const int tid = threadIdx.x;
    const int rr = tid >> 6;   // row slot within group of 4
    const int t = tid & 63;    // lane within row
    const int r0 = blockIdx.x * 16;

    for (int it = 0; it < 4; ++it) {
        const int r = r0 + it * 4 + rr;
        const float4 av = *(const float4*)(abase + (r << 8) + (t << 2));
        const float4 sv = *(const float4*)(sbase + (r << 8) + (t << 2));
        const int e0 = t << 2;
        Xb[rr][PIDX(e0 + 0)] = {av.x - sv.x, 0.f};
        Xb[rr][PIDX(e0 + 1)] = {av.y - sv.y, 0.f};
        Xb[rr][PIDX(e0 + 2)] = {av.z - sv.z, 0.f};
        Xb[rr][PIDX(e0 + 3)] = {av.w - sv.w, 0.f};
        __syncthreads();
        fft256_stages(Xb[rr], Yb[rr], t, true);
        // stash v = t, t+64, (t==0: 128) into transposed staging
        const int slot = it * 4 + rr;
        outT[t * 17 + slot] = Xb[rr][PIDX(t)];
        outT[(t + 64) * 17 + slot] = Xb[rr][PIDX(t + 64)];
        if (t == 0) outT[128 * 17 + slot] = Xb[rr][PIDX(128)];
        __syncthreads();  // protect Xb reuse next iter + outT completeness
    }

    // write [v][r0..r0+15] chunks: 128B contiguous per v
    float2* g = ws + (size_t)blockIdx.y * (129 * 256);
    for (int e = tid; e < 129 * 16; e += 256) {
        const int v = e >> 4, rl = e & 15;
        g[v * 256 + r0 + rl] = outT[v * 17 + rl];
    }
}

// Kernel 2: column FFTs (complex 256-pt) + weighted magnitude sum.
// grid = (33, nimg), block = 256 = 4 waves, one column per wave.
// NO atomics: one partial per block -> partial[img*33 + blockIdx.x].
__global__ __launch_bounds__(256) void k_colfft(const float2* __restrict__ ws,
                                                float* __restrict__ partial, int img0) {
    __shared__ float2 Xb[4][272];
    __shared__ float2 Yb[4][272];
    __shared__ float wsum[4];
    const int tid = threadIdx.x;
    const int w = tid >> 6, t = tid & 63;
    const int v = blockIdx.x * 4 + w;
    const bool active = v < 129;
    const float2* g = ws + ((size_t)blockIdx.y * 129 + (active ? v : 0)) * 256;
    if (active) {
#pragma unroll
        for (int q = 0; q < 4; ++q) Xb[w][PIDX(t + 64 * q)] = g[t + 64 * q];
    }
    __syncthreads();
    fft256_stages(Xb[w], Yb[w], t, active);
    float ssum = 0.f;
    if (active) {
#pragma unroll
        for (int q = 0; q < 4; ++q) {
            const float2 z = Xb[w][PIDX(t + 64 * q)];
            ssum += sqrtf(z.x * z.x + z.y * z.y);
        }
    }
#pragma unroll
    for (int off = 32; off; off >>= 1) ssum += __shfl_down(ssum, off);
    if (t == 0) {
        const float wgt = (v == 0 || v == 128) ? 1.f : 2.f;  // Hermitian symmetry weight
        wsum[w] = active ? ssum * wgt : 0.f;
    }
    __syncthreads();
    if (tid == 0) {
        const int img = img0 + blockIdx.y;
        partial[img * 33 + blockIdx.x] = wsum[0] + wsum[1] + wsum[2] + wsum[3];
    }
}

// partial layout [img][chunk=33], img-major: pair p's 3 images are 99 consecutive floats.
// pairSum[0..31] = sum|FFT(a-p)| per i;  pairSum[32 + 2i + k] = sum|FFT(a_i - n_j)|
__global__ void k_final(const float* __restrict__ partial, float* __restrict__ out) {
    __shared__ float ps[96];
    const int t = threadIdx.x;  // 128 threads
    if (t < 96) {
        float s = 0.f;
        const float* p = partial + t * 99;
        for (int e = 0; e < 99; ++e) s += p[e];
        ps[t] = s;
    }
    __syncthreads();
    if (t < 64) {  // wave 0: t = 2i+k
        const float inv = 1.f / 196608.f;  // mean over C*H*W
        const float dap = ps[t >> 1] * inv;
        const float dan = ps[32 + t] * inv + 1e-7f;
        float val = dap / dan;
#pragma unroll
        for (int off = 32; off; off >>= 1) val += __shfl_down(val, off);
        if (t == 0) out[0] = val * (1.f / 64.f);  // / (MULTI_N_NUM * B)
    }
}

extern "C" void kernel_launch(void* const* d_in, const int* in_sizes, int n_in,
                              void* d_out, int out_size, void* d_ws, size_t ws_size,
                              hipStream_t stream) {
    const float* A = (const float*)d_in[0];
    const float* P = (const float*)d_in[1];
    const float* N = (const float*)d_in[2];
    const int* negIdx = (const int*)d_in[3];

    float* partial = (float*)d_ws;  // 288*33 floats = 38016 B
    float2* inter = (float2*)((char*)d_ws + 40960);
    const size_t perImg = (size_t)129 * 256 * sizeof(float2);  // 264192 B
    size_t avail = ws_size > 40960 ? ws_size - 40960 : 0;
    int cap = (int)(avail / perImg);
    if (cap > 288) cap = 288;
    if (cap < 1) cap = 1;  // last resort

    for (int img0 = 0; img0 < 288; img0 += cap) {
        const int nimg = (288 - img0 < cap) ? (288 - img0) : cap;
        dim3 g1(16, nimg);
        k_rowfft<<<g1, dim3(256), 0, stream>>>(A, P, N, negIdx, inter, img0);
        dim3 g2(33, nimg);
        k_colfft<<<g2, dim3(256), 0, stream>>>(inter, partial, img0);
    }
    k_final<<<1, 128, 0, stream>>>(partial, (float*)d_out);
}

// Round 6
// 64.614 us; speedup vs baseline: 4.2342x; 1.1881x over previous
//
#include <hip/hip_runtime.h>
#include <math.h>

// Padded LDS index: breaks power-of-2 strides; injective for e in [0,256) -> [0,271)
#define PIDX(e) ((e) + ((e) >> 4))

__device__ __forceinline__ float2 cadd(float2 a, float2 b) { return {a.x + b.x, a.y + b.y}; }
__device__ __forceinline__ float2 csub(float2 a, float2 b) { return {a.x - b.x, a.y - b.y}; }
__device__ __forceinline__ float2 cmul(float2 a, float2 b) {
    return {a.x * b.x - a.y * b.y, a.x * b.y + a.y * b.x};
}

// 256-point Stockham radix-4 FFT, 64 threads per row, data in padded LDS buffers.
// Result ends up back in Xr (natural order). All threads of the block must call
// (barriers are uniform); inactive lanes pass active=false.
__device__ __forceinline__ void fft256_stages(float2* Xr, float2* Yr, int t, bool active) {
    float2* sbuf = Xr;
    float2* dbuf = Yr;
#pragma unroll
    for (int s = 0; s < 4; ++s) {
        if (active) {
            const int sh = 2 * s;
            const int mm = 1 << sh;       // 1,4,16,64
            const int ll = 64 >> sh;      // 64,16,4,1
            const int jj = t >> sh;       // j in [0,l)
            const int kk = t & (mm - 1);  // k in [0,m)
            float2 c0 = sbuf[PIDX(kk + mm * jj)];
            float2 c1 = sbuf[PIDX(kk + mm * (jj + ll))];
            float2 c2 = sbuf[PIDX(kk + mm * (jj + 2 * ll))];
            float2 c3 = sbuf[PIDX(kk + mm * (jj + 3 * ll))];
            float2 sa = cadd(c0, c2);
            float2 sb = csub(c0, c2);
            float2 sc = cadd(c1, c3);
            float2 sd = {c1.y - c3.y, c3.x - c1.x};  // -i*(c1-c3)
            float2 d0 = cadd(sa, sc);
            float2 d1 = cadd(sb, sd);
            float2 d2 = csub(sa, sc);
            float2 d3 = csub(sb, sd);
            // w = exp(-2*pi*i * jj / (4*ll)) = exp(-i * (2pi/256) * (jj << sh))
            const float ang = -0.024543692606170259f * (float)(jj << sh);
            float sy, cx;
            __sincosf(ang, &sy, &cx);
            float2 w1 = {cx, sy};
            float2 w2 = cmul(w1, w1);
            float2 w3 = cmul(w2, w1);
            const int ob = kk + 4 * mm * jj;
            dbuf[PIDX(ob)] = d0;
            dbuf[PIDX(ob + mm)] = cmul(w1, d1);
            dbuf[PIDX(ob + 2 * mm)] = cmul(w2, d2);
            dbuf[PIDX(ob + 3 * mm)] = cmul(w3, d3);
        }
        __syncthreads();
        float2* tmp = sbuf;
        sbuf = dbuf;
        dbuf = tmp;
    }
}

// Kernel 1: per image job (pair x channel), row FFTs of the real difference
// image via the two-rows-per-complex-FFT trick; keep v=0..128; write
// transposed [img][v][r] to ws.
// grid = (16 row-chunks, nimg), block = 256 = 4 waves; each wave packs 2 rows
// into one complex FFT, 2 iterations -> 16 rows per block.
__global__ __launch_bounds__(256) void k_rowfft(const float* __restrict__ A,
                                                const float* __restrict__ P,
                                                const float* __restrict__ N,
                                                const int* __restrict__ negIdx,
                                                float2* __restrict__ ws, int img0) {
    __shared__ float2 Xb[4][272];
    __shared__ float2 Yb[4][272];
    __shared__ float2 outT[129 * 17];  // [v][slot], stride 17 to dodge bank conflicts

    const int img = img0 + blockIdx.y;
    const int pair = img / 3;
    const int ch = img - pair * 3;
    int i, jn;
    const float* S;
    if (pair < 32) {  // anchor-positive pairs: j == i
        i = pair;
        jn = pair;
        S = P;
    } else {  // anchor-negative pairs: j = neg_idx[i][k]
        const int t2 = pair - 32;
        i = t2 >> 1;
        jn = negIdx[(i << 1) + (t2 & 1)];
        S = N;
    }
    const float* abase = A + ((size_t)(i * 3 + ch) << 16);
    const float* sbase = S + ((size_t)(jn * 3 + ch) << 16);

    const int tid = threadIdx.x;
    const int w = tid >> 6;   // wave id
    const int t = tid & 63;   // lane within wave
    const int r0 = blockIdx.x * 16;

    for (int it = 0; it < 2; ++it) {
        const int slot0 = it * 8 + 2 * w;      // local row slot (even)
        const int r = r0 + slot0;              // global row (pair r, r+1)
        const float4 a0 = *(const float4*)(abase + (r << 8) + (t << 2));
        const float4 a1 = *(const float4*)(abase + ((r + 1) << 8) + (t << 2));
        const float4 s0 = *(const float4*)(sbase + (r << 8) + (t << 2));
        const float4 s1 = *(const float4*)(sbase + ((r + 1) << 8) + (t << 2));
        const int e0 = t << 2;
        // z = d[r] + i*d[r+1]
        Xb[w][PIDX(e0 + 0)] = {a0.x - s0.x, a1.x - s1.x};
        Xb[w][PIDX(e0 + 1)] = {a0.y - s0.y, a1.y - s1.y};
        Xb[w][PIDX(e0 + 2)] = {a0.z - s0.z, a1.z - s1.z};
        Xb[w][PIDX(e0 + 3)] = {a0.w - s0.w, a1.w - s1.w};
        __syncthreads();
        fft256_stages(Xb[w], Yb[w], t, true);
        // Unpack Hermitian halves:
        //   D_r[v]   = 0.5*(Z[v] + conj(Z[-v]))
        //   D_r1[v]  = -0.5i*(Z[v] - conj(Z[-v]))
#pragma unroll
        for (int h = 0; h < 2; ++h) {
            const int v = t + 64 * h;                      // v in [0,128)
            const float2 p = Xb[w][PIDX(v)];
            const float2 m = Xb[w][PIDX((256 - v) & 255)];
            outT[v * 17 + slot0] = {0.5f * (p.x + m.x), 0.5f * (p.y - m.y)};
            outT[v * 17 + slot0 + 1] = {0.5f * (p.y + m.y), -0.5f * (p.x - m.x)};
        }
        if (t == 0) {  // v = 128: Z[128] is self-conjugate point
            const float2 p = Xb[w][PIDX(128)];
            outT[128 * 17 + slot0] = {p.x, 0.f};
            outT[128 * 17 + slot0 + 1] = {p.y, 0.f};
        }
        __syncthreads();  // protect Xb reuse next iter + outT completeness
    }

    // write [v][r0..r0+15] chunks: 128B contiguous per v
    float2* g = ws + (size_t)blockIdx.y * (129 * 256);
    for (int e = tid; e < 129 * 16; e += 256) {
        const int v = e >> 4, rl = e & 15;
        g[v * 256 + r0 + rl] = outT[v * 17 + rl];
    }
}

// Kernel 2: column FFTs (complex 256-pt) + weighted magnitude sum.
// grid = (33, nimg), block = 256 = 4 waves, one column per wave.
// NO atomics: one partial per block -> partial[img*33 + blockIdx.x].
__global__ __launch_bounds__(256) void k_colfft(const float2* __restrict__ ws,
                                                float* __restrict__ partial, int img0) {
    __shared__ float2 Xb[4][272];
    __shared__ float2 Yb[4][272];
    __shared__ float wsum[4];
    const int tid = threadIdx.x;
    const int w = tid >> 6, t = tid & 63;
    const int v = blockIdx.x * 4 + w;
    const bool active = v < 129;
    const float2* g = ws + ((size_t)blockIdx.y * 129 + (active ? v : 0)) * 256;
    if (active) {
#pragma unroll
        for (int q = 0; q < 4; ++q) Xb[w][PIDX(t + 64 * q)] = g[t + 64 * q];
    }
    __syncthreads();
    fft256_stages(Xb[w], Yb[w], t, active);
    float ssum = 0.f;
    if (active) {
#pragma unroll
        for (int q = 0; q < 4; ++q) {
            const float2 z = Xb[w][PIDX(t + 64 * q)];
            ssum += sqrtf(z.x * z.x + z.y * z.y);
        }
    }
#pragma unroll
    for (int off = 32; off; off >>= 1) ssum += __shfl_down(ssum, off);
    if (t == 0) {
        const float wgt = (v == 0 || v == 128) ? 1.f : 2.f;  // Hermitian symmetry weight
        wsum[w] = active ? ssum * wgt : 0.f;
    }
    __syncthreads();
    if (tid == 0) {
        const int img = img0 + blockIdx.y;
        partial[img * 33 + blockIdx.x] = wsum[0] + wsum[1] + wsum[2] + wsum[3];
    }
}

// partial layout [img][chunk=33], img-major: pair p's 3 images are 99 consecutive floats.
// pairSum[0..31] = sum|FFT(a-p)| per i;  pairSum[32 + 2i + k] = sum|FFT(a_i - n_j)|
__global__ void k_final(const float* __restrict__ partial, float* __restrict__ out) {
    __shared__ float ps[96];
    const int t = threadIdx.x;  // 128 threads
    if (t < 96) {
        float s = 0.f;
        const float* p = partial + t * 99;
        for (int e = 0; e < 99; ++e) s += p[e];
        ps[t] = s;
    }
    __syncthreads();
    if (t < 64) {  // wave 0: t = 2i+k
        const float inv = 1.f / 196608.f;  // mean over C*H*W
        const float dap = ps[t >> 1] * inv;
        const float dan = ps[32 + t] * inv + 1e-7f;
        float val = dap / dan;
#pragma unroll
        for (int off = 32; off; off >>= 1) val += __shfl_down(val, off);
        if (t == 0) out[0] = val * (1.f / 64.f);  // / (MULTI_N_NUM * B)
    }
}

extern "C" void kernel_launch(void* const* d_in, const int* in_sizes, int n_in,
                              void* d_out, int out_size, void* d_ws, size_t ws_size,
                              hipStream_t stream) {
    const float* A = (const float*)d_in[0];
    const float* P = (const float*)d_in[1];
    const float* N = (const float*)d_in[2];
    const int* negIdx = (const int*)d_in[3];

    float* partial = (float*)d_ws;  // 288*33 floats = 38016 B
    float2* inter = (float2*)((char*)d_ws + 40960);
    const size_t perImg = (size_t)129 * 256 * sizeof(float2);  // 264192 B
    size_t avail = ws_size > 40960 ? ws_size - 40960 : 0;
    int cap = (int)(avail / perImg);
    if (cap > 288) cap = 288;
    if (cap < 1) cap = 1;  // last resort

    for (int img0 = 0; img0 < 288; img0 += cap) {
        const int nimg = (288 - img0 < cap) ? (288 - img0) : cap;
        dim3 g1(16, nimg);
        k_rowfft<<<g1, dim3(256), 0, stream>>>(A, P, N, negIdx, inter, img0);
        dim3 g2(33, nimg);
        k_colfft<<<g2, dim3(256), 0, stream>>>(inter, partial, img0);
    }
    k_final<<<1, 128, 0, stream>>>(partial, (float*)d_out);
}

// Round 7
// 56.483 us; speedup vs baseline: 4.8437x; 1.1439x over previous
//
#include <hip/hip_runtime.h>
#include <hip/hip_fp16.h>
#include <math.h>

// Padded LDS index: breaks power-of-2 strides; injective for e in [0,256) -> [0,271)
#define PIDX(e) ((e) + ((e) >> 4))

// Wave-local "sync": waves own disjoint LDS slices; same-wave DS ops are
// processed in order by the LDS pipe, so we only need to stop the COMPILER
// from reordering/caching LDS accesses across this point.
#define WAVE_SYNC()                          \
    do {                                     \
        __builtin_amdgcn_wave_barrier();     \
        asm volatile("" ::: "memory");       \
    } while (0)

__device__ __forceinline__ float2 cadd(float2 a, float2 b) { return {a.x + b.x, a.y + b.y}; }
__device__ __forceinline__ float2 csub(float2 a, float2 b) { return {a.x - b.x, a.y - b.y}; }
__device__ __forceinline__ float2 cmul(float2 a, float2 b) {
    return {a.x * b.x - a.y * b.y, a.x * b.y + a.y * b.x};
}

// 256-point Stockham radix-4 FFT owned by ONE wave (64 lanes), data in this
// wave's padded LDS buffers. Result ends back in X (natural order).
__device__ __forceinline__ void fft256_wave(float2* X, float2* Y, int t) {
    float2* sbuf = X;
    float2* dbuf = Y;
#pragma unroll
    for (int s = 0; s < 4; ++s) {
        const int sh = 2 * s;
        const int mm = 1 << sh;       // 1,4,16,64
        const int ll = 64 >> sh;      // 64,16,4,1
        const int jj = t >> sh;       // j in [0,l)
        const int kk = t & (mm - 1);  // k in [0,m)
        float2 c0 = sbuf[PIDX(kk + mm * jj)];
        float2 c1 = sbuf[PIDX(kk + mm * (jj + ll))];
        float2 c2 = sbuf[PIDX(kk + mm * (jj + 2 * ll))];
        float2 c3 = sbuf[PIDX(kk + mm * (jj + 3 * ll))];
        float2 sa = cadd(c0, c2);
        float2 sb = csub(c0, c2);
        float2 sc = cadd(c1, c3);
        float2 sd = {c1.y - c3.y, c3.x - c1.x};  // -i*(c1-c3)
        float2 d0 = cadd(sa, sc);
        float2 d1 = cadd(sb, sd);
        float2 d2 = csub(sa, sc);
        float2 d3 = csub(sb, sd);
        // w = exp(-i * (2pi/256) * (jj << sh))
        const float ang = -0.024543692606170259f * (float)(jj << sh);
        float sy, cx;
        __sincosf(ang, &sy, &cx);
        float2 w1 = {cx, sy};
        float2 w2 = cmul(w1, w1);
        float2 w3 = cmul(w2, w1);
        const int ob = kk + 4 * mm * jj;
        dbuf[PIDX(ob)] = d0;
        dbuf[PIDX(ob + mm)] = cmul(w1, d1);
        dbuf[PIDX(ob + 2 * mm)] = cmul(w2, d2);
        dbuf[PIDX(ob + 3 * mm)] = cmul(w3, d3);
        WAVE_SYNC();
        float2* tmp = sbuf;
        sbuf = dbuf;
        dbuf = tmp;
    }
}

// Kernel 1: per image job (pair x channel), row FFTs of the real difference
// image via the two-rows-per-complex-FFT trick. Output: f16 spectra,
// transposed [img][v][r] with v in [0,128): v=0 holds the PACKED real pair
// (D_r[0], D_r[128]) as (lo,hi) of a half2; v=1..127 hold complex D_r[v].
// grid = (8 row-chunks, nimg), block = 256 = 4 waves; each wave: 4 packed
// FFTs (8 rows). 32 rows per block.
__global__ __launch_bounds__(256) void k_rowfft(const float* __restrict__ A,
                                                const float* __restrict__ P,
                                                const float* __restrict__ N,
                                                const int* __restrict__ negIdx,
                                                __half2* __restrict__ ws, int img0) {
    __shared__ float2 Xb[4][272];
    __shared__ float2 Yb[4][272];
    __shared__ __half2 outT[128 * 33];  // [v][slot], stride 33 (odd -> conflict-free)

    const int img = img0 + blockIdx.y;
    const int pair = img / 3;
    const int ch = img - pair * 3;
    int i, jn;
    const float* S;
    if (pair < 32) {  // anchor-positive pairs: j == i
        i = pair;
        jn = pair;
        S = P;
    } else {  // anchor-negative pairs: j = neg_idx[i][k]
        const int t2 = pair - 32;
        i = t2 >> 1;
        jn = negIdx[(i << 1) + (t2 & 1)];
        S = N;
    }
    const float* abase = A + ((size_t)(i * 3 + ch) << 16);
    const float* sbase = S + ((size_t)(jn * 3 + ch) << 16);

    const int tid = threadIdx.x;
    const int w = tid >> 6;   // wave id
    const int t = tid & 63;   // lane within wave
    const int r0 = blockIdx.x * 32;

    for (int it = 0; it < 4; ++it) {
        const int prl = it * 4 + w;       // packed-FFT index within block [0,16)
        const int slot = 2 * prl;         // even row slot
        const int r = r0 + slot;          // global rows r, r+1
        const float4 a0 = *(const float4*)(abase + (r << 8) + (t << 2));
        const float4 a1 = *(const float4*)(abase + ((r + 1) << 8) + (t << 2));
        const float4 s0 = *(const float4*)(sbase + (r << 8) + (t << 2));
        const float4 s1 = *(const float4*)(sbase + ((r + 1) << 8) + (t << 2));
        const int e0 = t << 2;
        // z = d[r] + i*d[r+1]
        Xb[w][PIDX(e0 + 0)] = {a0.x - s0.x, a1.x - s1.x};
        Xb[w][PIDX(e0 + 1)] = {a0.y - s0.y, a1.y - s1.y};
        Xb[w][PIDX(e0 + 2)] = {a0.z - s0.z, a1.z - s1.z};
        Xb[w][PIDX(e0 + 3)] = {a0.w - s0.w, a1.w - s1.w};
        WAVE_SYNC();
        fft256_wave(Xb[w], Yb[w], t);
        // Unpack Hermitian halves:
        //   D_r[v]  = 0.5*(Z[v] + conj(Z[-v]));  D_r1[v] = -0.5i*(Z[v] - conj(Z[-v]))
        {  // h = 0: v = t (lane 0 emits the packed v=0/v=128 column instead)
            const float2 p = Xb[w][PIDX(t)];
            if (t == 0) {
                const float2 z128 = Xb[w][PIDX(128)];
                // D_r[0]=Re Z0, D_r1[0]=Im Z0; D_r[128]=Re Z128, D_r1[128]=Im Z128
                outT[0 * 33 + slot] = __floats2half2_rn(p.x, z128.x);
                outT[0 * 33 + slot + 1] = __floats2half2_rn(p.y, z128.y);
            } else {
                const float2 m = Xb[w][PIDX(256 - t)];
                outT[t * 33 + slot] = __floats2half2_rn(0.5f * (p.x + m.x), 0.5f * (p.y - m.y));
                outT[t * 33 + slot + 1] =
                    __floats2half2_rn(0.5f * (p.y + m.y), -0.5f * (p.x - m.x));
            }
        }
        {  // h = 1: v = t + 64 in [64,128)
            const int v = t + 64;
            const float2 p = Xb[w][PIDX(v)];
            const float2 m = Xb[w][PIDX(192 - t)];
            outT[v * 33 + slot] = __floats2half2_rn(0.5f * (p.x + m.x), 0.5f * (p.y - m.y));
            outT[v * 33 + slot + 1] = __floats2half2_rn(0.5f * (p.y + m.y), -0.5f * (p.x - m.x));
        }
        WAVE_SYNC();  // outT/Xb reuse next iter (wave-local hazard only)
    }

    __syncthreads();  // all waves' outT slots complete

    // write [v][r0..r0+31] chunks: 128B contiguous per v
    __half2* g = ws + (size_t)blockIdx.y * (128 * 256);
    for (int e = tid; e < 128 * 32; e += 256) {
        const int v = e >> 5, rl = e & 31;
        g[v * 256 + r0 + rl] = outT[v * 33 + rl];
    }
}

// Kernel 2: column FFTs (complex 256-pt) + weighted magnitude sum.
// grid = (32, nimg), block = 256 = 4 waves, one column per wave (all active).
// v=0 is the packed real pair (col0, col128): unpack magnitudes weight 1;
// v>=1: weight 2 (Hermitian v-symmetry).
__global__ __launch_bounds__(256) void k_colfft(const __half2* __restrict__ ws,
                                                float* __restrict__ partial, int img0) {
    __shared__ float2 Xb[4][272];
    __shared__ float2 Yb[4][272];
    __shared__ float wsum[4];
    const int tid = threadIdx.x;
    const int w = tid >> 6, t = tid & 63;
    const int v = blockIdx.x * 4 + w;  // [0,128)
    const __half2* g = ws + ((size_t)blockIdx.y * 128 + v) * 256;
    // one float4 = 4 half2 = rows 4t..4t+3
    const float4 raw = *(const float4*)(g + 4 * t);
    const __half2* hp = (const __half2*)&raw;
#pragma unroll
    for (int k = 0; k < 4; ++k) {
        const float2 z = __half22float2(hp[k]);
        Xb[w][PIDX(4 * t + k)] = z;
    }
    WAVE_SYNC();
    fft256_wave(Xb[w], Yb[w], t);
    float ssum = 0.f;
    if (v == 0) {
#pragma unroll
        for (int q = 0; q < 4; ++q) {
            const int u = t + 64 * q;
            const float2 zu = Xb[w][PIDX(u)];
            const float2 zm = Xb[w][PIDX((256 - u) & 255)];
            // C_A[u] = 0.5(W[u]+conj(W[-u]));  C_B[u] = -0.5i(W[u]-conj(W[-u]))
            const float ax = 0.5f * (zu.x + zm.x), ay = 0.5f * (zu.y - zm.y);
            const float bx = 0.5f * (zu.y + zm.y), by = -0.5f * (zu.x - zm.x);
            ssum += sqrtf(ax * ax + ay * ay) + sqrtf(bx * bx + by * by);
        }
    } else {
#pragma unroll
        for (int q = 0; q < 4; ++q) {
            const float2 z = Xb[w][PIDX(t + 64 * q)];
            ssum += 2.f * sqrtf(z.x * z.x + z.y * z.y);
        }
    }
#pragma unroll
    for (int off = 32; off; off >>= 1) ssum += __shfl_down(ssum, off);
    if (t == 0) wsum[w] = ssum;
    __syncthreads();
    if (tid == 0) {
        const int img = img0 + blockIdx.y;
        partial[img * 32 + blockIdx.x] = wsum[0] + wsum[1] + wsum[2] + wsum[3];
    }
}

// partial layout [img][chunk=32], img-major: pair p's 3 images = 96 consecutive floats.
// pairSum[0..31] = sum|FFT(a-p)| per i;  pairSum[32 + 2i + k] = sum|FFT(a_i - n_j)|
__global__ void k_final(const float* __restrict__ partial, float* __restrict__ out) {
    __shared__ float ps[96];
    const int t = threadIdx.x;  // 128 threads
    if (t < 96) {
        float s = 0.f;
        const float* p = partial + t * 96;
        for (int e = 0; e < 96; ++e) s += p[e];
        ps[t] = s;
    }
    __syncthreads();
    if (t < 64) {  // wave 0: t = 2i+k
        const float inv = 1.f / 196608.f;  // mean over C*H*W
        const float dap = ps[t >> 1] * inv;
        const float dan = ps[32 + t] * inv + 1e-7f;
        float val = dap / dan;
#pragma unroll
        for (int off = 32; off; off >>= 1) val += __shfl_down(val, off);
        if (t == 0) out[0] = val * (1.f / 64.f);  // / (MULTI_N_NUM * B)
    }
}

extern "C" void kernel_launch(void* const* d_in, const int* in_sizes, int n_in,
                              void* d_out, int out_size, void* d_ws, size_t ws_size,
                              hipStream_t stream) {
    const float* A = (const float*)d_in[0];
    const float* P = (const float*)d_in[1];
    const float* N = (const float*)d_in[2];
    const int* negIdx = (const int*)d_in[3];

    float* partial = (float*)d_ws;  // 288*32 floats = 36864 B
    __half2* inter = (__half2*)((char*)d_ws + 40960);
    const size_t perImg = (size_t)128 * 256 * sizeof(__half2);  // 131072 B
    size_t avail = ws_size > 40960 ? ws_size - 40960 : 0;
    int cap = (int)(avail / perImg);
    if (cap > 288) cap = 288;
    if (cap < 1) cap = 1;  // last resort

    for (int img0 = 0; img0 < 288; img0 += cap) {
        const int nimg = (288 - img0 < cap) ? (288 - img0) : cap;
        dim3 g1(8, nimg);
        k_rowfft<<<g1, dim3(256), 0, stream>>>(A, P, N, negIdx, inter, img0);
        dim3 g2(32, nimg);
        k_colfft<<<g2, dim3(256), 0, stream>>>(inter, partial, img0);
    }
    k_final<<<1, 128, 0, stream>>>(partial, (float*)d_out);
}

// Round 8
// 50.763 us; speedup vs baseline: 5.3895x; 1.1127x over previous
//
#include <hip/hip_runtime.h>
#include <hip/hip_fp16.h>
#include <math.h>

// Padded LDS index: breaks power-of-2 strides; injective for e in [0,256) -> [0,271)
#define PIDX(e) ((e) + ((e) >> 4))

// Wave-local "sync": waves own disjoint LDS slices; same-wave DS ops are
// processed in order by the LDS pipe, so we only need to stop the COMPILER
// from reordering/caching LDS accesses across this point.
#define WAVE_SYNC()                          \
    do {                                     \
        __builtin_amdgcn_wave_barrier();     \
        asm volatile("" ::: "memory");       \
    } while (0)

__device__ __forceinline__ float2 cadd(float2 a, float2 b) { return {a.x + b.x, a.y + b.y}; }
__device__ __forceinline__ float2 csub(float2 a, float2 b) { return {a.x - b.x, a.y - b.y}; }
__device__ __forceinline__ float2 cmul(float2 a, float2 b) {
    return {a.x * b.x - a.y * b.y, a.x * b.y + a.y * b.x};
}

// 256-point Stockham radix-4 FFT owned by ONE wave (64 lanes), data in this
// wave's padded LDS buffers. Result ends back in X (natural order).
__device__ __forceinline__ void fft256_wave(float2* X, float2* Y, int t) {
    float2* sbuf = X;
    float2* dbuf = Y;
#pragma unroll
    for (int s = 0; s < 4; ++s) {
        const int sh = 2 * s;
        const int mm = 1 << sh;       // 1,4,16,64
        const int ll = 64 >> sh;      // 64,16,4,1
        const int jj = t >> sh;       // j in [0,l)
        const int kk = t & (mm - 1);  // k in [0,m)
        float2 c0 = sbuf[PIDX(kk + mm * jj)];
        float2 c1 = sbuf[PIDX(kk + mm * (jj + ll))];
        float2 c2 = sbuf[PIDX(kk + mm * (jj + 2 * ll))];
        float2 c3 = sbuf[PIDX(kk + mm * (jj + 3 * ll))];
        float2 sa = cadd(c0, c2);
        float2 sb = csub(c0, c2);
        float2 sc = cadd(c1, c3);
        float2 sd = {c1.y - c3.y, c3.x - c1.x};  // -i*(c1-c3)
        float2 d0 = cadd(sa, sc);
        float2 d1 = cadd(sb, sd);
        float2 d2 = csub(sa, sc);
        float2 d3 = csub(sb, sd);
        // w = exp(-i * (2pi/256) * (jj << sh))
        const float ang = -0.024543692606170259f * (float)(jj << sh);
        float sy, cx;
        __sincosf(ang, &sy, &cx);
        float2 w1 = {cx, sy};
        float2 w2 = cmul(w1, w1);
        float2 w3 = cmul(w2, w1);
        const int ob = kk + 4 * mm * jj;
        dbuf[PIDX(ob)] = d0;
        dbuf[PIDX(ob + mm)] = cmul(w1, d1);
        dbuf[PIDX(ob + 2 * mm)] = cmul(w2, d2);
        dbuf[PIDX(ob + 3 * mm)] = cmul(w3, d3);
        WAVE_SYNC();
        float2* tmp = sbuf;
        sbuf = dbuf;
        dbuf = tmp;
    }
}

__device__ __forceinline__ void load4(const float* __restrict__ abase,
                                      const float* __restrict__ sbase, int r, int t, float4& a0,
                                      float4& a1, float4& s0, float4& s1) {
    a0 = *(const float4*)(abase + (r << 8) + (t << 2));
    a1 = *(const float4*)(abase + ((r + 1) << 8) + (t << 2));
    s0 = *(const float4*)(sbase + (r << 8) + (t << 2));
    s1 = *(const float4*)(sbase + ((r + 1) << 8) + (t << 2));
}

// Kernel 1: per image job (pair x channel), row FFTs of the real difference
// image via the two-rows-per-complex-FFT trick. Output: f16 spectra,
// transposed [img][v][r] with v in [0,128): v=0 holds the PACKED real pair
// (D_r[0], D_r[128]) as (lo,hi) of a half2; v=1..127 hold complex D_r[v].
// grid = (8 row-chunks, nimg), block = 256 = 4 waves; each wave: 4 packed
// FFTs (8 rows), with register prefetch of the next iteration's rows.
__global__ __launch_bounds__(256) void k_rowfft(const float* __restrict__ A,
                                                const float* __restrict__ P,
                                                const float* __restrict__ N,
                                                const int* __restrict__ negIdx,
                                                __half2* __restrict__ ws, int img0) {
    __shared__ float2 Xb[4][272];
    __shared__ float2 Yb[4][272];
    __shared__ __half2 outT[128 * 33];  // [v][slot], stride 33 (odd -> conflict-free)

    const int img = img0 + blockIdx.y;
    const int pair = img / 3;
    const int ch = img - pair * 3;
    int i, jn;
    const float* S;
    if (pair < 32) {  // anchor-positive pairs: j == i
        i = pair;
        jn = pair;
        S = P;
    } else {  // anchor-negative pairs: j = neg_idx[i][k]
        const int t2 = pair - 32;
        i = t2 >> 1;
        jn = negIdx[(i << 1) + (t2 & 1)];
        S = N;
    }
    const float* abase = A + ((size_t)(i * 3 + ch) << 16);
    const float* sbase = S + ((size_t)(jn * 3 + ch) << 16);

    const int tid = threadIdx.x;
    const int w = tid >> 6;   // wave id
    const int t = tid & 63;   // lane within wave
    const int r0 = blockIdx.x * 32;

    float4 pa0, pa1, ps0, ps1;
    load4(abase, sbase, r0 + 2 * w, t, pa0, pa1, ps0, ps1);

    for (int it = 0; it < 4; ++it) {
        const int slot = 2 * (it * 4 + w);  // even row slot
        const float4 a0 = pa0, a1 = pa1, s0 = ps0, s1 = ps1;
        // issue next iteration's loads BEFORE consuming current (hides HBM latency
        // under the whole FFT; waits are vmcnt-counted at use)
        if (it < 3) load4(abase, sbase, r0 + 2 * ((it + 1) * 4 + w), t, pa0, pa1, ps0, ps1);
        const int e0 = t << 2;
        // z = d[r] + i*d[r+1]
        Xb[w][PIDX(e0 + 0)] = {a0.x - s0.x, a1.x - s1.x};
        Xb[w][PIDX(e0 + 1)] = {a0.y - s0.y, a1.y - s1.y};
        Xb[w][PIDX(e0 + 2)] = {a0.z - s0.z, a1.z - s1.z};
        Xb[w][PIDX(e0 + 3)] = {a0.w - s0.w, a1.w - s1.w};
        WAVE_SYNC();
        fft256_wave(Xb[w], Yb[w], t);
        // Unpack Hermitian halves:
        //   D_r[v]  = 0.5*(Z[v] + conj(Z[-v]));  D_r1[v] = -0.5i*(Z[v] - conj(Z[-v]))
        {  // h = 0: v = t (lane 0 emits the packed v=0/v=128 column instead)
            const float2 p = Xb[w][PIDX(t)];
            if (t == 0) {
                const float2 z128 = Xb[w][PIDX(128)];
                // D_r[0]=Re Z0, D_r1[0]=Im Z0; D_r[128]=Re Z128, D_r1[128]=Im Z128
                outT[0 * 33 + slot] = __floats2half2_rn(p.x, z128.x);
                outT[0 * 33 + slot + 1] = __floats2half2_rn(p.y, z128.y);
            } else {
                const float2 m = Xb[w][PIDX(256 - t)];
                outT[t * 33 + slot] = __floats2half2_rn(0.5f * (p.x + m.x), 0.5f * (p.y - m.y));
                outT[t * 33 + slot + 1] =
                    __floats2half2_rn(0.5f * (p.y + m.y), -0.5f * (p.x - m.x));
            }
        }
        {  // h = 1: v = t + 64 in [64,128)
            const int v = t + 64;
            const float2 p = Xb[w][PIDX(v)];
            const float2 m = Xb[w][PIDX(192 - t)];
            outT[v * 33 + slot] = __floats2half2_rn(0.5f * (p.x + m.x), 0.5f * (p.y - m.y));
            outT[v * 33 + slot + 1] = __floats2half2_rn(0.5f * (p.y + m.y), -0.5f * (p.x - m.x));
        }
        WAVE_SYNC();  // outT/Xb reuse next iter (wave-local hazard only)
    }

    __syncthreads();  // all waves' outT slots complete

    // write [v][r0..r0+31] chunks: one float4 (4 half2) per thread per iter
    __half2* g = ws + (size_t)blockIdx.y * (128 * 256);
    for (int e = tid; e < 128 * 8; e += 256) {
        const int v = e >> 3, rl4 = (e & 7) << 2;
        float4 val;
        __half2* vp = (__half2*)&val;
#pragma unroll
        for (int k = 0; k < 4; ++k) vp[k] = outT[v * 33 + rl4 + k];
        *(float4*)(g + v * 256 + r0 + rl4) = val;
    }
}

// Kernel 2: column FFTs (complex 256-pt) + weighted magnitude sum.
// grid = (8, nimg), block = 256 = 4 waves; each wave owns 4 consecutive
// columns, processed serially with register prefetch of the next column.
// v=0 is the packed real pair (col0, col128): weight 1; v>=1: weight 2.
__global__ __launch_bounds__(256) void k_colfft(const __half2* __restrict__ ws,
                                                float* __restrict__ partial, int img0) {
    __shared__ float2 Xb[4][272];
    __shared__ float2 Yb[4][272];
    __shared__ float wsum[4];
    const int tid = threadIdx.x;
    const int w = tid >> 6, t = tid & 63;
    const int vbase = blockIdx.x * 16 + w * 4;  // [0,128)
    const __half2* gimg = ws + (size_t)blockIdx.y * (128 * 256);

    float acc = 0.f;
    float4 nraw = *(const float4*)(gimg + (size_t)vbase * 256 + 4 * t);
    for (int j = 0; j < 4; ++j) {
        const int v = vbase + j;
        const float4 raw = nraw;
        if (j < 3) nraw = *(const float4*)(gimg + (size_t)(v + 1) * 256 + 4 * t);
        const __half2* hp = (const __half2*)&raw;
#pragma unroll
        for (int k = 0; k < 4; ++k) {
            const float2 z = __half22float2(hp[k]);
            Xb[w][PIDX(4 * t + k)] = z;
        }
        WAVE_SYNC();
        fft256_wave(Xb[w], Yb[w], t);
        float ssum = 0.f;
        if (v == 0) {
#pragma unroll
            for (int q = 0; q < 4; ++q) {
                const int u = t + 64 * q;
                const float2 zu = Xb[w][PIDX(u)];
                const float2 zm = Xb[w][PIDX((256 - u) & 255)];
                // C_A[u] = 0.5(W[u]+conj(W[-u]));  C_B[u] = -0.5i(W[u]-conj(W[-u]))
                const float ax = 0.5f * (zu.x + zm.x), ay = 0.5f * (zu.y - zm.y);
                const float bx = 0.5f * (zu.y + zm.y), by = -0.5f * (zu.x - zm.x);
                ssum += sqrtf(ax * ax + ay * ay) + sqrtf(bx * bx + by * by);
            }
        } else {
#pragma unroll
            for (int q = 0; q < 4; ++q) {
                const float2 z = Xb[w][PIDX(t + 64 * q)];
                ssum += 2.f * sqrtf(z.x * z.x + z.y * z.y);
            }
        }
        acc += ssum;
        WAVE_SYNC();  // Xb fully consumed before next column's staging
    }
#pragma unroll
    for (int off = 32; off; off >>= 1) acc += __shfl_down(acc, off);
    if (t == 0) wsum[w] = acc;
    __syncthreads();
    if (tid == 0) {
        const int img = img0 + blockIdx.y;
        partial[img * 8 + blockIdx.x] = wsum[0] + wsum[1] + wsum[2] + wsum[3];
    }
}

// partial layout [img][chunk=8], img-major: pair p's 3 images = 24 consecutive floats.
// pairSum[0..31] = sum|FFT(a-p)| per i;  pairSum[32 + 2i + k] = sum|FFT(a_i - n_j)|
__global__ void k_final(const float* __restrict__ partial, float* __restrict__ out) {
    __shared__ float ps[96];
    const int t = threadIdx.x;  // 128 threads
    if (t < 96) {
        float s = 0.f;
        const float* p = partial + t * 24;
        for (int e = 0; e < 24; ++e) s += p[e];
        ps[t] = s;
    }
    __syncthreads();
    if (t < 64) {  // wave 0: t = 2i+k
        const float inv = 1.f / 196608.f;  // mean over C*H*W
        const float dap = ps[t >> 1] * inv;
        const float dan = ps[32 + t] * inv + 1e-7f;
        float val = dap / dan;
#pragma unroll
        for (int off = 32; off; off >>= 1) val += __shfl_down(val, off);
        if (t == 0) out[0] = val * (1.f / 64.f);  // / (MULTI_N_NUM * B)
    }
}

extern "C" void kernel_launch(void* const* d_in, const int* in_sizes, int n_in,
                              void* d_out, int out_size, void* d_ws, size_t ws_size,
                              hipStream_t stream) {
    const float* A = (const float*)d_in[0];
    const float* P = (const float*)d_in[1];
    const float* N = (const float*)d_in[2];
    const int* negIdx = (const int*)d_in[3];

    float* partial = (float*)d_ws;  // 288*8 floats = 9216 B
    __half2* inter = (__half2*)((char*)d_ws + 40960);
    const size_t perImg = (size_t)128 * 256 * sizeof(__half2);  // 131072 B
    size_t avail = ws_size > 40960 ? ws_size - 40960 : 0;
    int cap = (int)(avail / perImg);
    if (cap > 288) cap = 288;
    if (cap < 1) cap = 1;  // last resort

    for (int img0 = 0; img0 < 288; img0 += cap) {
        const int nimg = (288 - img0 < cap) ? (288 - img0) : cap;
        dim3 g1(8, nimg);
        k_rowfft<<<g1, dim3(256), 0, stream>>>(A, P, N, negIdx, inter, img0);
        dim3 g2(8, nimg);
        k_colfft<<<g2, dim3(256), 0, stream>>>(inter, partial, img0);
    }
    k_final<<<1, 128, 0, stream>>>(partial, (float*)d_out);
}

// Round 9
// 46.913 us; speedup vs baseline: 5.8318x; 1.0821x over previous
//
#include <hip/hip_runtime.h>
#include <hip/hip_fp16.h>
#include <math.h>

// Padded LDS index: breaks power-of-2 strides; injective for e in [0,256) -> [0,271)
#define PIDX(e) ((e) + ((e) >> 4))

// Wave-local "sync": waves own disjoint LDS slices; same-wave DS ops are
// processed in order by the LDS pipe, so we only need a COMPILER fence.
#define WAVE_SYNC()                          \
    do {                                     \
        __builtin_amdgcn_wave_barrier();     \
        asm volatile("" ::: "memory");       \
    } while (0)

__device__ __forceinline__ float2 cadd(float2 a, float2 b) { return {a.x + b.x, a.y + b.y}; }
__device__ __forceinline__ float2 csub(float2 a, float2 b) { return {a.x - b.x, a.y - b.y}; }
__device__ __forceinline__ float2 cmul(float2 a, float2 b) {
    return {a.x * b.x - a.y * b.y, a.x * b.y + a.y * b.x};
}

// Stage 0 (radix-4, stride-64 partners) computed entirely in registers from
// z_q = element[t + 64q]; writes its outputs (natural Stockham order) to X.
__device__ __forceinline__ void fft256_stage0_reg(float2 z0, float2 z1, float2 z2, float2 z3,
                                                  float2* X, int t) {
    float2 sa = cadd(z0, z2);
    float2 sb = csub(z0, z2);
    float2 sc = cadd(z1, z3);
    float2 sd = {z1.y - z3.y, z3.x - z1.x};  // -i*(z1-z3)
    float2 d0 = cadd(sa, sc);
    float2 d1 = cadd(sb, sd);
    float2 d2 = csub(sa, sc);
    float2 d3 = csub(sb, sd);
    const float ang = -0.024543692606170259f * (float)t;  // -(2pi/256)*t
    float sy, cx;
    __sincosf(ang, &sy, &cx);
    float2 w1 = {cx, sy};
    float2 w2 = cmul(w1, w1);
    float2 w3 = cmul(w2, w1);
    const int ob = t << 2;
    X[PIDX(ob)] = d0;
    X[PIDX(ob + 1)] = cmul(w1, d1);
    X[PIDX(ob + 2)] = cmul(w2, d2);
    X[PIDX(ob + 3)] = cmul(w3, d3);
    WAVE_SYNC();
}

// Stages 1..3 of the 256-pt Stockham radix-4 FFT, single LDS buffer.
// Key fact: read addresses are ALWAYS {t, t+64, t+128, t+192} (kk+mm*jj == t),
// so read-all -> fence -> write-all is safe within one wave (same-wave DS ops
// execute in order). Result lands in natural order.
__device__ __forceinline__ void fft256_stages123(float2* X, int t) {
#pragma unroll
    for (int s = 1; s < 4; ++s) {
        float2 c0 = X[PIDX(t)];
        float2 c1 = X[PIDX(t + 64)];
        float2 c2 = X[PIDX(t + 128)];
        float2 c3 = X[PIDX(t + 192)];
        WAVE_SYNC();  // all lanes' reads issued before any write below
        const int sh = 2 * s;
        const int mm = 1 << sh;       // 4,16,64
        const int jj = t >> sh;
        const int kk = t & (mm - 1);
        float2 sa = cadd(c0, c2);
        float2 sb = csub(c0, c2);
        float2 sc = cadd(c1, c3);
        float2 sd = {c1.y - c3.y, c3.x - c1.x};  // -i*(c1-c3)
        float2 d0 = cadd(sa, sc);
        float2 d1 = cadd(sb, sd);
        float2 d2 = csub(sa, sc);
        float2 d3 = csub(sb, sd);
        const float ang = -0.024543692606170259f * (float)(jj << sh);
        float sy, cx;
        __sincosf(ang, &sy, &cx);
        float2 w1 = {cx, sy};
        float2 w2 = cmul(w1, w1);
        float2 w3 = cmul(w2, w1);
        const int ob = kk + 4 * mm * jj;
        X[PIDX(ob)] = d0;
        X[PIDX(ob + mm)] = cmul(w1, d1);
        X[PIDX(ob + 2 * mm)] = cmul(w2, d2);
        X[PIDX(ob + 3 * mm)] = cmul(w3, d3);
        WAVE_SYNC();
    }
}

// 16 strided dword loads: lane t gets element cols {t+64q} of rows r, r+1 for
// both inputs. Each instr reads 256B contiguous across the wave (coalesced).
__device__ __forceinline__ void load16(const float* __restrict__ abase,
                                       const float* __restrict__ sbase, int r, int t, float* a0,
                                       float* a1, float* s0, float* s1) {
#pragma unroll
    for (int q = 0; q < 4; ++q) {
        a0[q] = abase[(r << 8) + t + (q << 6)];
        a1[q] = abase[((r + 1) << 8) + t + (q << 6)];
        s0[q] = sbase[(r << 8) + t + (q << 6)];
        s1[q] = sbase[((r + 1) << 8) + t + (q << 6)];
    }
}

// Kernel 1: row FFTs of the real difference image, two rows per complex FFT.
// Output f16 spectra transposed [img][v][r], v in [0,128): v=0 packs (D[0],D[128]).
// grid = (8 row-chunks, nimg), block = 256 = 4 waves; 4 packed FFTs per wave,
// register prefetch of next iteration's rows, stage 0 in registers.
__global__ __launch_bounds__(256) void k_rowfft(const float* __restrict__ A,
                                                const float* __restrict__ P,
                                                const float* __restrict__ N,
                                                const int* __restrict__ negIdx,
                                                __half2* __restrict__ ws, int img0) {
    __shared__ float2 Xb[4][272];       // 8.7 KB (single-buffer FFT)
    __shared__ __half2 outT[128 * 33];  // 16.9 KB, stride 33 -> conflict-free

    const int img = img0 + blockIdx.y;
    const int pair = img / 3;
    const int ch = img - pair * 3;
    int i, jn;
    const float* S;
    if (pair < 32) {  // anchor-positive pairs: j == i
        i = pair;
        jn = pair;
        S = P;
    } else {  // anchor-negative pairs: j = neg_idx[i][k]
        const int t2 = pair - 32;
        i = t2 >> 1;
        jn = negIdx[(i << 1) + (t2 & 1)];
        S = N;
    }
    const float* abase = A + ((size_t)(i * 3 + ch) << 16);
    const float* sbase = S + ((size_t)(jn * 3 + ch) << 16);

    const int tid = threadIdx.x;
    const int w = tid >> 6;   // wave id
    const int t = tid & 63;   // lane
    const int r0 = blockIdx.x * 32;

    float pa0[4], pa1[4], ps0[4], ps1[4];
    load16(abase, sbase, r0 + 2 * w, t, pa0, pa1, ps0, ps1);

    for (int it = 0; it < 4; ++it) {
        const int slot = 2 * (it * 4 + w);  // even row slot in [0,32)
        float2 z[4];
#pragma unroll
        for (int q = 0; q < 4; ++q) z[q] = {pa0[q] - ps0[q], pa1[q] - ps1[q]};
        // prefetch next iteration's rows; flies under the whole FFT
        if (it < 3) load16(abase, sbase, r0 + 2 * ((it + 1) * 4 + w), t, pa0, pa1, ps0, ps1);
        fft256_stage0_reg(z[0], z[1], z[2], z[3], Xb[w], t);
        fft256_stages123(Xb[w], t);
        // Unpack Hermitian halves:
        //   D_r[v]  = 0.5*(Z[v] + conj(Z[-v]));  D_r1[v] = -0.5i*(Z[v] - conj(Z[-v]))
        {  // v = t (lane 0 emits the packed v=0/v=128 column instead)
            const float2 p = Xb[w][PIDX(t)];
            if (t == 0) {
                const float2 z128 = Xb[w][PIDX(128)];
                outT[0 * 33 + slot] = __floats2half2_rn(p.x, z128.x);
                outT[0 * 33 + slot + 1] = __floats2half2_rn(p.y, z128.y);
            } else {
                const float2 m = Xb[w][PIDX(256 - t)];
                outT[t * 33 + slot] = __floats2half2_rn(0.5f * (p.x + m.x), 0.5f * (p.y - m.y));
                outT[t * 33 + slot + 1] =
                    __floats2half2_rn(0.5f * (p.y + m.y), -0.5f * (p.x - m.x));
            }
        }
        {  // v = t + 64
            const int v = t + 64;
            const float2 p = Xb[w][PIDX(v)];
            const float2 m = Xb[w][PIDX(192 - t)];
            outT[v * 33 + slot] = __floats2half2_rn(0.5f * (p.x + m.x), 0.5f * (p.y - m.y));
            outT[v * 33 + slot + 1] = __floats2half2_rn(0.5f * (p.y + m.y), -0.5f * (p.x - m.x));
        }
        WAVE_SYNC();  // Xb/outT reuse next iter (wave-local hazard only)
    }

    __syncthreads();  // all waves' outT slots complete

    // write [v][r0..r0+31] chunks: one float4 (4 half2) per thread per iter
    __half2* g = ws + (size_t)blockIdx.y * (128 * 256);
    for (int e = tid; e < 128 * 8; e += 256) {
        const int v = e >> 3, rl4 = (e & 7) << 2;
        float4 val;
        __half2* vp = (__half2*)&val;
#pragma unroll
        for (int k = 0; k < 4; ++k) vp[k] = outT[v * 33 + rl4 + k];
        *(float4*)(g + v * 256 + r0 + rl4) = val;
    }
}

// Kernel 2: column FFTs (complex 256-pt) + weighted magnitude sum.
// grid = (8, nimg), block = 256 = 4 waves; each wave owns 4 consecutive
// columns serially with register prefetch; stage 0 in registers.
// v=0 is the packed real pair (col0, col128): weight 1; v>=1: weight 2.
__global__ __launch_bounds__(256) void k_colfft(const __half2* __restrict__ ws,
                                                float* __restrict__ partial, int img0) {
    __shared__ float2 Xb[4][272];  // 8.7 KB -> thread-capped occupancy
    __shared__ float wsum[4];
    const int tid = threadIdx.x;
    const int w = tid >> 6, t = tid & 63;
    const int vbase = blockIdx.x * 16 + w * 4;  // [0,128)
    const __half2* gimg = ws + (size_t)blockIdx.y * (128 * 256);

    float acc = 0.f;
    __half2 cur[4], nxt[4];
#pragma unroll
    for (int q = 0; q < 4; ++q) cur[q] = gimg[(size_t)vbase * 256 + t + (q << 6)];
    for (int j = 0; j < 4; ++j) {
        const int v = vbase + j;
        if (j < 3) {
#pragma unroll
            for (int q = 0; q < 4; ++q) nxt[q] = gimg[(size_t)(v + 1) * 256 + t + (q << 6)];
        }
        float2 z[4];
#pragma unroll
        for (int q = 0; q < 4; ++q) z[q] = __half22float2(cur[q]);
        fft256_stage0_reg(z[0], z[1], z[2], z[3], Xb[w], t);
        fft256_stages123(Xb[w], t);
        float ssum = 0.f;
        if (v == 0) {
#pragma unroll
            for (int q = 0; q < 4; ++q) {
                const int u = t + 64 * q;
                const float2 zu = Xb[w][PIDX(u)];
                const float2 zm = Xb[w][PIDX((256 - u) & 255)];
                // C_A[u] = 0.5(W[u]+conj(W[-u]));  C_B[u] = -0.5i(W[u]-conj(W[-u]))
                const float ax = 0.5f * (zu.x + zm.x), ay = 0.5f * (zu.y - zm.y);
                const float bx = 0.5f * (zu.y + zm.y), by = -0.5f * (zu.x - zm.x);
                ssum += sqrtf(ax * ax + ay * ay) + sqrtf(bx * bx + by * by);
            }
        } else {
#pragma unroll
            for (int q = 0; q < 4; ++q) {
                const float2 zz = Xb[w][PIDX(t + 64 * q)];
                ssum += 2.f * sqrtf(zz.x * zz.x + zz.y * zz.y);
            }
        }
        acc += ssum;
#pragma unroll
        for (int q = 0; q < 4; ++q) cur[q] = nxt[q];
        WAVE_SYNC();  // Xb fully consumed before next column's stage-0 writes
    }
#pragma unroll
    for (int off = 32; off; off >>= 1) acc += __shfl_down(acc, off);
    if (t == 0) wsum[w] = acc;
    __syncthreads();
    if (tid == 0) {
        const int img = img0 + blockIdx.y;
        partial[img * 8 + blockIdx.x] = wsum[0] + wsum[1] + wsum[2] + wsum[3];
    }
}

// partial layout [img][chunk=8], img-major: pair p's 3 images = 24 consecutive floats.
// pairSum[0..31] = sum|FFT(a-p)| per i;  pairSum[32 + 2i + k] = sum|FFT(a_i - n_j)|
__global__ void k_final(const float* __restrict__ partial, float* __restrict__ out) {
    __shared__ float ps[96];
    const int t = threadIdx.x;  // 128 threads
    if (t < 96) {
        float s = 0.f;
        const float* p = partial + t * 24;
        for (int e = 0; e < 24; ++e) s += p[e];
        ps[t] = s;
    }
    __syncthreads();
    if (t < 64) {  // wave 0: t = 2i+k
        const float inv = 1.f / 196608.f;  // mean over C*H*W
        const float dap = ps[t >> 1] * inv;
        const float dan = ps[32 + t] * inv + 1e-7f;
        float val = dap / dan;
#pragma unroll
        for (int off = 32; off; off >>= 1) val += __shfl_down(val, off);
        if (t == 0) out[0] = val * (1.f / 64.f);  // / (MULTI_N_NUM * B)
    }
}

extern "C" void kernel_launch(void* const* d_in, const int* in_sizes, int n_in,
                              void* d_out, int out_size, void* d_ws, size_t ws_size,
                              hipStream_t stream) {
    const float* A = (const float*)d_in[0];
    const float* P = (const float*)d_in[1];
    const float* N = (const float*)d_in[2];
    const int* negIdx = (const int*)d_in[3];

    float* partial = (float*)d_ws;  // 288*8 floats = 9216 B
    __half2* inter = (__half2*)((char*)d_ws + 40960);
    const size_t perImg = (size_t)128 * 256 * sizeof(__half2);  // 131072 B
    size_t avail = ws_size > 40960 ? ws_size - 40960 : 0;
    int cap = (int)(avail / perImg);
    if (cap > 288) cap = 288;
    if (cap < 1) cap = 1;  // last resort

    for (int img0 = 0; img0 < 288; img0 += cap) {
        const int nimg = (288 - img0 < cap) ? (288 - img0) : cap;
        dim3 g1(8, nimg);
        k_rowfft<<<g1, dim3(256), 0, stream>>>(A, P, N, negIdx, inter, img0);
        dim3 g2(8, nimg);
        k_colfft<<<g2, dim3(256), 0, stream>>>(inter, partial, img0);
    }
    k_final<<<1, 128, 0, stream>>>(partial, (float*)d_out);
}

// Round 10
// 45.769 us; speedup vs baseline: 5.9776x; 1.0250x over previous
//
#include <hip/hip_runtime.h>
#include <hip/hip_fp16.h>
#include <math.h>

// Padded LDS index: breaks power-of-2 strides; injective for e in [0,256) -> [0,271)
#define PIDX(e) ((e) + ((e) >> 4))

// Wave-local "sync": waves own disjoint LDS slices; same-wave DS ops are
// processed in order by the LDS pipe, so we only need a COMPILER fence.
#define WAVE_SYNC()                          \
    do {                                     \
        __builtin_amdgcn_wave_barrier();     \
        asm volatile("" ::: "memory");       \
    } while (0)

__device__ __forceinline__ float2 cadd(float2 a, float2 b) { return {a.x + b.x, a.y + b.y}; }
__device__ __forceinline__ float2 csub(float2 a, float2 b) { return {a.x - b.x, a.y - b.y}; }
__device__ __forceinline__ float2 cmul(float2 a, float2 b) {
    return {a.x * b.x - a.y * b.y, a.x * b.y + a.y * b.x};
}
__device__ __forceinline__ float2 shfl64(float2 v, int src) {
    return {__shfl(v.x, src), __shfl(v.y, src)};
}

// Radix-4 butterfly (DIF): d0..d3 from c0..c3.
#define BFLY4(c0, c1, c2, c3, d0, d1, d2, d3)            \
    {                                                    \
        float2 sa = cadd(c0, c2);                        \
        float2 sb = csub(c0, c2);                        \
        float2 sc = cadd(c1, c3);                        \
        float2 sd = {(c1).y - (c3).y, (c3).x - (c1).x}; \
        d0 = cadd(sa, sc);                               \
        d1 = cadd(sb, sd);                               \
        d2 = csub(sa, sc);                               \
        d3 = csub(sb, sd);                               \
    }

// Per-lane twiddle set for one stage (constant across all FFTs of the kernel).
struct Tw {
    float2 w1, w2, w3;
};
__device__ __forceinline__ Tw make_tw(int idx) {
    const float ang = -0.024543692606170259f * (float)idx;  // -(2pi/256)*idx
    float sy, cx;
    __sincosf(ang, &sy, &cx);
    Tw tw;
    tw.w1 = {cx, sy};
    tw.w2 = cmul(tw.w1, tw.w1);
    tw.w3 = cmul(tw.w2, tw.w1);
    return tw;
}

// Stage 0 (stride-64 partners, within-lane): registers -> LDS (natural order).
__device__ __forceinline__ void fft_stage0(float2 z0, float2 z1, float2 z2, float2 z3, float2* X,
                                           int t, const Tw& tw) {
    float2 d0, d1, d2, d3;
    BFLY4(z0, z1, z2, z3, d0, d1, d2, d3);
    const int ob = t << 2;
    X[PIDX(ob)] = d0;
    X[PIDX(ob + 1)] = cmul(tw.w1, d1);
    X[PIDX(ob + 2)] = cmul(tw.w2, d2);
    X[PIDX(ob + 3)] = cmul(tw.w3, d3);
    WAVE_SYNC();
}

// Middle stage (s=1: sh=2, s=2: sh=4), single LDS buffer: reads are always
// {t, t+64, t+128, t+192}; read-all -> fence -> write-all (same-wave DS order).
template <int SH>
__device__ __forceinline__ void fft_stage_mid(float2* X, int t, const Tw& tw) {
    float2 c0 = X[PIDX(t)];
    float2 c1 = X[PIDX(t + 64)];
    float2 c2 = X[PIDX(t + 128)];
    float2 c3 = X[PIDX(t + 192)];
    WAVE_SYNC();
    float2 d0, d1, d2, d3;
    BFLY4(c0, c1, c2, c3, d0, d1, d2, d3);
    const int mm = 1 << SH;
    const int jj = t >> SH;
    const int kk = t & (mm - 1);
    const int ob = kk + 4 * mm * jj;
    X[PIDX(ob)] = d0;
    X[PIDX(ob + mm)] = cmul(tw.w1, d1);
    X[PIDX(ob + 2 * mm)] = cmul(tw.w2, d2);
    X[PIDX(ob + 3 * mm)] = cmul(tw.w3, d3);
    WAVE_SYNC();
}

// Stage 3 (jj=0 -> identity twiddle; writes would land back at {t+64q}):
// keep the result in registers. d_q = Z[t + 64q].
__device__ __forceinline__ void fft_stage3_reg(float2* X, int t, float2& d0, float2& d1,
                                               float2& d2, float2& d3) {
    float2 c0 = X[PIDX(t)];
    float2 c1 = X[PIDX(t + 64)];
    float2 c2 = X[PIDX(t + 128)];
    float2 c3 = X[PIDX(t + 192)];
    WAVE_SYNC();  // reads done before this buffer is overwritten by next stage0
    BFLY4(c0, c1, c2, c3, d0, d1, d2, d3);
}

// 16 strided dword loads: lane t gets element cols {t+64q} of rows r, r+1 for
// both inputs. Each instr reads 256B contiguous across the wave (coalesced).
__device__ __forceinline__ void load16(const float* __restrict__ abase,
                                       const float* __restrict__ sbase, int r, int t, float* a0,
                                       float* a1, float* s0, float* s1) {
#pragma unroll
    for (int q = 0; q < 4; ++q) {
        a0[q] = abase[(r << 8) + t + (q << 6)];
        a1[q] = abase[((r + 1) << 8) + t + (q << 6)];
        s0[q] = sbase[(r << 8) + t + (q << 6)];
        s1[q] = sbase[((r + 1) << 8) + t + (q << 6)];
    }
}

// Kernel 1: row FFTs of the real difference image, two rows per complex FFT.
// Output f16 spectra transposed [img][v][r], v in [0,128): v=0 packs (D[0],D[128]).
// grid = (8 row-chunks, nimg), block = 256 = 4 waves; 4 packed FFTs per wave,
// register prefetch, stage0+stage3 in registers, hoisted twiddles.
__global__ __launch_bounds__(256) void k_rowfft(const float* __restrict__ A,
                                                const float* __restrict__ P,
                                                const float* __restrict__ N,
                                                const int* __restrict__ negIdx,
                                                __half2* __restrict__ ws, int img0) {
    __shared__ float2 Xb[4][272];       // 8.7 KB (single-buffer FFT)
    __shared__ __half2 outT[128 * 33];  // 16.9 KB, stride 33 -> conflict-free

    const int img = img0 + blockIdx.y;
    const int pair = img / 3;
    const int ch = img - pair * 3;
    int i, jn;
    const float* S;
    if (pair < 32) {  // anchor-positive pairs: j == i
        i = pair;
        jn = pair;
        S = P;
    } else {  // anchor-negative pairs: j = neg_idx[i][k]
        const int t2 = pair - 32;
        i = t2 >> 1;
        jn = negIdx[(i << 1) + (t2 & 1)];
        S = N;
    }
    const float* abase = A + ((size_t)(i * 3 + ch) << 16);
    const float* sbase = S + ((size_t)(jn * 3 + ch) << 16);

    const int tid = threadIdx.x;
    const int w = tid >> 6;   // wave id
    const int t = tid & 63;   // lane
    const int r0 = blockIdx.x * 32;

    // Hoisted per-lane twiddles (constant for every FFT in this kernel).
    const Tw tw0 = make_tw(t);
    const Tw tw1 = make_tw(t & ~3);
    const Tw tw2 = make_tw(t & ~15);
    const int ridx = (64 - t) & 63;  // reversal shuffle index

    float pa0[4], pa1[4], ps0[4], ps1[4];
    load16(abase, sbase, r0 + 2 * w, t, pa0, pa1, ps0, ps1);

    for (int it = 0; it < 4; ++it) {
        const int slot = 2 * (it * 4 + w);  // even row slot in [0,32)
        float2 z[4];
#pragma unroll
        for (int q = 0; q < 4; ++q) z[q] = {pa0[q] - ps0[q], pa1[q] - ps1[q]};
        // prefetch next iteration's rows; flies under the whole FFT
        if (it < 3) load16(abase, sbase, r0 + 2 * ((it + 1) * 4 + w), t, pa0, pa1, ps0, ps1);
        fft_stage0(z[0], z[1], z[2], z[3], Xb[w], t, tw0);
        fft_stage_mid<2>(Xb[w], t, tw1);
        fft_stage_mid<4>(Xb[w], t, tw2);
        float2 d0, d1, d2, d3;  // d_q = Z[t + 64q]
        fft_stage3_reg(Xb[w], t, d0, d1, d2, d3);
        // Unpack Hermitian halves (all register/shuffle, no LDS):
        //   D_r[v] = 0.5*(Z[v] + conj(Z[-v]));  D_r1[v] = -0.5i*(Z[v] - conj(Z[-v]))
        const float2 m3 = shfl64(d3, ridx);  // Z[256-t] for t>=1
        const float2 m2 = shfl64(d2, ridx);  // Z[192-t] for t>=1
        if (t == 0) {
            // v=0 packs (D_r[0], D_r[128]) = (Re/Im Z[0], Re/Im Z[128])
            outT[slot] = __floats2half2_rn(d0.x, d2.x);
            outT[slot + 1] = __floats2half2_rn(d0.y, d2.y);
        } else {
            outT[t * 33 + slot] = __floats2half2_rn(0.5f * (d0.x + m3.x), 0.5f * (d0.y - m3.y));
            outT[t * 33 + slot + 1] =
                __floats2half2_rn(0.5f * (d0.y + m3.y), -0.5f * (d0.x - m3.x));
        }
        {  // v = t + 64;  m = Z[192-t] (lane 0: Z[192] = own d3)
            const int v = t + 64;
            const float2 mm2 = (t == 0) ? d3 : m2;
            outT[v * 33 + slot] = __floats2half2_rn(0.5f * (d1.x + mm2.x), 0.5f * (d1.y - mm2.y));
            outT[v * 33 + slot + 1] =
                __floats2half2_rn(0.5f * (d1.y + mm2.y), -0.5f * (d1.x - mm2.x));
        }
        WAVE_SYNC();  // outT slot writes complete before Xb reuse next iter
    }

    __syncthreads();  // all waves' outT slots complete

    // write [v][r0..r0+31] chunks: one float4 (4 half2) per thread per iter
    __half2* g = ws + (size_t)blockIdx.y * (128 * 256);
    for (int e = tid; e < 128 * 8; e += 256) {
        const int v = e >> 3, rl4 = (e & 7) << 2;
        float4 val;
        __half2* vp = (__half2*)&val;
#pragma unroll
        for (int k = 0; k < 4; ++k) vp[k] = outT[v * 33 + rl4 + k];
        *(float4*)(g + v * 256 + r0 + rl4) = val;
    }
}

// Kernel 2: column FFTs (complex 256-pt) + weighted magnitude sum.
// grid = (8, nimg), block = 256 = 4 waves; each wave owns 4 consecutive
// columns serially with register prefetch; stages 0 & 3 in registers,
// magnitudes own-lane (LDS-free) except the rare v==0 wave.
// v=0 is the packed real pair (col0, col128): weight 1; v>=1: weight 2.
__global__ __launch_bounds__(256) void k_colfft(const __half2* __restrict__ ws,
                                                float* __restrict__ partial, int img0) {
    __shared__ float2 Xb[4][272];  // 8.7 KB
    __shared__ float wsum[4];
    const int tid = threadIdx.x;
    const int w = tid >> 6, t = tid & 63;
    const int vbase = blockIdx.x * 16 + w * 4;  // [0,128)
    const __half2* gimg = ws + (size_t)blockIdx.y * (128 * 256);

    const Tw tw0 = make_tw(t);
    const Tw tw1 = make_tw(t & ~3);
    const Tw tw2 = make_tw(t & ~15);

    float acc = 0.f;
    __half2 cur[4], nxt[4];
#pragma unroll
    for (int q = 0; q < 4; ++q) cur[q] = gimg[(size_t)vbase * 256 + t + (q << 6)];
    for (int j = 0; j < 4; ++j) {
        const int v = vbase + j;
        if (j < 3) {
#pragma unroll
            for (int q = 0; q < 4; ++q) nxt[q] = gimg[(size_t)(v + 1) * 256 + t + (q << 6)];
        }
        float2 z[4];
#pragma unroll
        for (int q = 0; q < 4; ++q) z[q] = __half22float2(cur[q]);
        fft_stage0(z[0], z[1], z[2], z[3], Xb[w], t, tw0);
        fft_stage_mid<2>(Xb[w], t, tw1);
        fft_stage_mid<4>(Xb[w], t, tw2);
        float2 d0, d1, d2, d3;  // d_q = W[t + 64q]
        fft_stage3_reg(Xb[w], t, d0, d1, d2, d3);
        float ssum = 0.f;
        if (v == 0) {  // wave-uniform rare path: needs W[-u]; use LDS round trip
            Xb[w][PIDX(t)] = d0;
            Xb[w][PIDX(t + 64)] = d1;
            Xb[w][PIDX(t + 128)] = d2;
            Xb[w][PIDX(t + 192)] = d3;
            WAVE_SYNC();
#pragma unroll
            for (int q = 0; q < 4; ++q) {
                const int u = t + 64 * q;
                const float2 zu = Xb[w][PIDX(u)];
                const float2 zm = Xb[w][PIDX((256 - u) & 255)];
                // C_A[u] = 0.5(W[u]+conj(W[-u]));  C_B[u] = -0.5i(W[u]-conj(W[-u]))
                const float ax = 0.5f * (zu.x + zm.x), ay = 0.5f * (zu.y - zm.y);
                const float bx = 0.5f * (zu.y + zm.y), by = -0.5f * (zu.x - zm.x);
                ssum += sqrtf(ax * ax + ay * ay) + sqrtf(bx * bx + by * by);
            }
        } else {
            ssum = 2.f * (sqrtf(d0.x * d0.x + d0.y * d0.y) + sqrtf(d1.x * d1.x + d1.y * d1.y) +
                          sqrtf(d2.x * d2.x + d2.y * d2.y) + sqrtf(d3.x * d3.x + d3.y * d3.y));
        }
        acc += ssum;
#pragma unroll
        for (int q = 0; q < 4; ++q) cur[q] = nxt[q];
        WAVE_SYNC();  // Xb fully consumed before next column's stage-0 writes
    }
#pragma unroll
    for (int off = 32; off; off >>= 1) acc += __shfl_down(acc, off);
    if (t == 0) wsum[w] = acc;
    __syncthreads();
    if (tid == 0) {
        const int img = img0 + blockIdx.y;
        partial[img * 8 + blockIdx.x] = wsum[0] + wsum[1] + wsum[2] + wsum[3];
    }
}

// partial layout [img][chunk=8], img-major: pair p's 3 images = 24 consecutive floats.
// pairSum[0..31] = sum|FFT(a-p)| per i;  pairSum[32 + 2i + k] = sum|FFT(a_i - n_j)|
__global__ void k_final(const float* __restrict__ partial, float* __restrict__ out) {
    __shared__ float ps[96];
    const int t = threadIdx.x;  // 128 threads
    if (t < 96) {
        float s = 0.f;
        const float* p = partial + t * 24;
        for (int e = 0; e < 24; ++e) s += p[e];
        ps[t] = s;
    }
    __syncthreads();
    if (t < 64) {  // wave 0: t = 2i+k
        const float inv = 1.f / 196608.f;  // mean over C*H*W
        const float dap = ps[t >> 1] * inv;
        const float dan = ps[32 + t] * inv + 1e-7f;
        float val = dap / dan;
#pragma unroll
        for (int off = 32; off; off >>= 1) val += __shfl_down(val, off);
        if (t == 0) out[0] = val * (1.f / 64.f);  // / (MULTI_N_NUM * B)
    }
}

extern "C" void kernel_launch(void* const* d_in, const int* in_sizes, int n_in,
                              void* d_out, int out_size, void* d_ws, size_t ws_size,
                              hipStream_t stream) {
    const float* A = (const float*)d_in[0];
    const float* P = (const float*)d_in[1];
    const float* N = (const float*)d_in[2];
    const int* negIdx = (const int*)d_in[3];

    float* partial = (float*)d_ws;  // 288*8 floats = 9216 B
    __half2* inter = (__half2*)((char*)d_ws + 40960);
    const size_t perImg = (size_t)128 * 256 * sizeof(__half2);  // 131072 B
    size_t avail = ws_size > 40960 ? ws_size - 40960 : 0;
    int cap = (int)(avail / perImg);
    if (cap > 288) cap = 288;
    if (cap < 1) cap = 1;  // last resort

    for (int img0 = 0; img0 < 288; img0 += cap) {
        const int nimg = (288 - img0 < cap) ? (288 - img0) : cap;
        dim3 g1(8, nimg);
        k_rowfft<<<g1, dim3(256), 0, stream>>>(A, P, N, negIdx, inter, img0);
        dim3 g2(8, nimg);
        k_colfft<<<g2, dim3(256), 0, stream>>>(inter, partial, img0);
    }
    k_final<<<1, 128, 0, stream>>>(partial, (float*)d_out);
}